// Round 16
// baseline (977.305 us; speedup 1.0000x reference)
//
#include <hip/hip_runtime.h>
#include <hip/hip_bf16.h>

#define D_ 128
#define DK_ 1280
#define K_ 10

typedef __attribute__((ext_vector_type(8))) short bh8;   // 8 bf16 = 4 VGPR (MFMA A/B frag)
typedef __attribute__((ext_vector_type(4))) short bh4;
typedef __attribute__((ext_vector_type(4))) float f32x4; // MFMA C/D frag

__device__ __forceinline__ short f2b(float f) {
    unsigned u = __builtin_bit_cast(unsigned, f);
    u += 0x7fffu + ((u >> 16) & 1u);          // RNE
    return (short)(u >> 16);
}
__device__ __forceinline__ float b2f(short s) {
    unsigned u = ((unsigned)(unsigned short)s) << 16;
    return __builtin_bit_cast(float, u);
}
__device__ __forceinline__ float tanh_fast(float x) {
    float e = __expf(2.f * x);
    return 1.f - __fdividef(2.f, e + 1.f);
}
__device__ __forceinline__ f32x4 mfma16(bh8 a, bh8 b, f32x4 c) {
    return __builtin_amdgcn_mfma_f32_16x16x32_bf16(a, b, c, 0, 0, 0);
}

// block-exclusive scan of one int per thread (256 threads)
__device__ __forceinline__ int blk_excl_scan(int v, int t) {
    __shared__ int wp[4];
    int lane = t & 63, w = t >> 6;
    int s = v;
    for (int o = 1; o < 64; o <<= 1) {
        int pv = __shfl_up(s, o);
        if (lane >= o) s += pv;
    }
    if (lane == 63) wp[w] = s;
    __syncthreads();
    if (t == 0) {
        int a = 0;
#pragma unroll
        for (int k = 0; k < 4; ++k) { int x = wp[k]; wp[k] = a; a += x; }
    }
    __syncthreads();
    int r = s - v + wp[w];
    __syncthreads();
    return r;
}

// ---------------- fused f32->bf16 conversions + uavg ----------------
__global__ __launch_bounds__(256) void cvt_all(
    const float* __restrict__ us, const float* __restrict__ ut,
    const float* __restrict__ usp, const float* __restrict__ is_,
    short* __restrict__ usb, short* __restrict__ utb,
    short* __restrict__ uspb, short* __restrict__ uavg, short* __restrict__ isb,
    int n4u, int n4i)
{
    int i = blockIdx.x * 256 + threadIdx.x;
    if (i < n4u) {
        float4 a = ((const float4*)us)[i];
        float4 b = ((const float4*)ut)[i];
        float4 c = ((const float4*)usp)[i];
        bh4 sa, sb, sc, sv;
        sa[0] = f2b(a.x); sa[1] = f2b(a.y); sa[2] = f2b(a.z); sa[3] = f2b(a.w);
        sb[0] = f2b(b.x); sb[1] = f2b(b.y); sb[2] = f2b(b.z); sb[3] = f2b(b.w);
        sc[0] = f2b(c.x); sc[1] = f2b(c.y); sc[2] = f2b(c.z); sc[3] = f2b(c.w);
        sv[0] = f2b(0.5f * (a.x + c.x)); sv[1] = f2b(0.5f * (a.y + c.y));
        sv[2] = f2b(0.5f * (a.z + c.z)); sv[3] = f2b(0.5f * (a.w + c.w));
        ((bh4*)usb)[i] = sa; ((bh4*)utb)[i] = sb;
        ((bh4*)uspb)[i] = sc; ((bh4*)uavg)[i] = sv;
    } else if (i < n4u + n4i) {
        int j = i - n4u;
        float4 v = ((const float4*)is_)[j];
        bh4 s;
        s[0] = f2b(v.x); s[1] = f2b(v.y); s[2] = f2b(v.z); s[3] = f2b(v.w);
        ((bh4*)isb)[j] = s;
    }
}

// ---------------- pack all weights: W[K][N] f32 -> bf16 MFMA-fragment order ----------------
struct PackArgs {
    const float* W[8];
    short* o[8];
    int K[8];
    int N[8];
};
__global__ __launch_bounds__(256) void pack_all(PackArgs pa)
{
    int seg = blockIdx.y;
    int K = pa.K[seg], N = pa.N[seg];
    int total = K * N;
    int o = blockIdx.x * 256 + threadIdx.x;
    if (o >= total) return;
    const float* W = pa.W[seg];
    short* out = pa.o[seg];
    int j    = o & 7;
    int lane = (o >> 3) & 63;
    int rest = o >> 9;
    int KK = K >> 5;
    int kk = rest % KK;
    int tile = rest / KK;
    int k = kk * 32 + (lane >> 4) * 8 + j;
    int n = tile * 16 + (lane & 15);
    out[o] = f2b(W[(size_t)k * N + n]);
}

// ---------------- CSR build: bucket histogram (LDS-aggregated) ----------------
__global__ __launch_bounds__(256) void bhist_kernel(
    const int* __restrict__ eu, const int* __restrict__ ei,
    int* __restrict__ bcu, int* __restrict__ bci,
    int E, int shu, int shi, int nbu, int nbi)
{
    __shared__ int hu[160], hi[160];
    int t = threadIdx.x;
    int base = blockIdx.x * 4096;
    if (t < 160) { hu[t] = 0; hi[t] = 0; }
    __syncthreads();
    int n = min(4096, E - base);
#pragma unroll 4
    for (int k = 0; k < 16; ++k) {
        int idx = k * 256 + t;
        if (idx < n) {
            atomicAdd(&hu[eu[base + idx] >> shu], 1);
            atomicAdd(&hi[ei[base + idx] >> shi], 1);
        }
    }
    __syncthreads();
    if (t < nbu && hu[t]) atomicAdd(&bcu[t], hu[t]);
    if (t < nbi && hi[t]) atomicAdd(&bci[t], hi[t]);
}

// ---------------- CSR build: bucket base scan ----------------
__global__ __launch_bounds__(256) void binit_kernel(
    const int* __restrict__ bcu, int* __restrict__ gcu, int* __restrict__ bbu, int nbu,
    const int* __restrict__ bci, int* __restrict__ gci, int* __restrict__ bbi, int nbi,
    int E)
{
    int t = threadIdx.x;
    {
        int v = (t < nbu) ? bcu[t] : 0;
        int ex = blk_excl_scan(v, t);
        if (t < nbu) { gcu[t] = ex; bbu[t] = ex; }
        if (t == 0) bbu[nbu] = E;
    }
    __syncthreads();
    {
        int v = (t < nbi) ? bci[t] : 0;
        int ex = blk_excl_scan(v, t);
        if (t < nbi) { gci[t] = ex; bbi[t] = ex; }
        if (t == 0) bbi[nbi] = E;
    }
}

// ---------------- CSR build: partition edges into buckets (4B packed entries) ----------------
// u-side entry: (u&511)<<16 | item   (item < 65536)
// i-side entry: (i&255)<<17 | user   (user < 131072)
__global__ __launch_bounds__(256) void partition_kernel(
    const int* __restrict__ eu, const int* __restrict__ ei,
    int* __restrict__ gcu, int* __restrict__ gci,
    unsigned* __restrict__ ebu, unsigned* __restrict__ ebi,
    int E, int shu, int shi, int nbu, int nbi)
{
    __shared__ int hu[160], hi[160];
    int t = threadIdx.x;
    int base = blockIdx.x * 4096;
    if (t < 160) { hu[t] = 0; hi[t] = 0; }
    __syncthreads();
    int n = min(4096, E - base);
    int us[16], is_[16];
#pragma unroll 4
    for (int k = 0; k < 16; ++k) {
        int idx = k * 256 + t;
        if (idx < n) {
            us[k] = eu[base + idx];
            is_[k] = ei[base + idx];
            atomicAdd(&hu[us[k] >> shu], 1);
            atomicAdd(&hi[is_[k] >> shi], 1);
        } else us[k] = -1;
    }
    __syncthreads();
    if (t < nbu) { int c = hu[t]; hu[t] = c ? atomicAdd(&gcu[t], c) : 0; }
    if (t < nbi) { int c = hi[t]; hi[t] = c ? atomicAdd(&gci[t], c) : 0; }
    __syncthreads();
#pragma unroll 4
    for (int k = 0; k < 16; ++k) {
        if (us[k] >= 0) {
            int p1 = atomicAdd(&hu[us[k] >> shu], 1);
            ebu[p1] = ((unsigned)(us[k] & 511) << 16) | (unsigned)is_[k];
            int p2 = atomicAdd(&hi[is_[k] >> shi], 1);
            ebi[p2] = ((unsigned)(is_[k] & 255) << 17) | (unsigned)us[k];
        }
    }
}

// ---------------- CSR build: per-bucket offsets + adjacency (u and i sides) ----------------
__global__ __launch_bounds__(256) void fill2_all(
    const unsigned* __restrict__ ebu, const int* __restrict__ bbu,
    int* __restrict__ off_u, int* __restrict__ end_u, int* __restrict__ adj_u,
    int NBU, int U,
    const unsigned* __restrict__ ebi, const int* __restrict__ bbi,
    int* __restrict__ off_i, int* __restrict__ end_i, int* __restrict__ adj_i, int I)
{
    __shared__ int lcnt[512];
    __shared__ int lcur[512];
    bool isU = (int)blockIdx.x < NBU;
    const unsigned* ebuf = isU ? ebu : ebi;
    const int* bbase  = isU ? bbu : bbi;
    int* off  = isU ? off_u : off_i;
    int* end_ = isU ? end_u : end_i;
    int* adj  = isU ? adj_u : adj_i;
    int span_sh = isU ? 9 : 8;
    int pay_sh = isU ? 16 : 17;
    unsigned pmask = (1u << pay_sh) - 1u;
    int nrows = isU ? U : I;
    int b = isU ? blockIdx.x : blockIdx.x - NBU;

    int t = threadIdx.x;
    int rbase = b << span_sh;
    int span = min(1 << span_sh, nrows - rbase);
    int regbeg = bbase[b], regend = bbase[b + 1];
    for (int j = t; j < span; j += 256) lcnt[j] = 0;
    __syncthreads();
    for (int e = regbeg + t; e < regend; e += 256)
        atomicAdd(&lcnt[ebuf[e] >> pay_sh], 1);
    __syncthreads();
    int c0 = (2 * t < span) ? lcnt[2 * t] : 0;
    int c1 = (2 * t + 1 < span) ? lcnt[2 * t + 1] : 0;
    int ex = blk_excl_scan(c0 + c1, t);
    if (2 * t < span) {
        int beg = regbeg + ex;
        off[rbase + 2 * t] = beg;
        end_[rbase + 2 * t] = beg + c0;
        lcur[2 * t] = beg;
    }
    if (2 * t + 1 < span) {
        int beg = regbeg + ex + c0;
        off[rbase + 2 * t + 1] = beg;
        end_[rbase + 2 * t + 1] = beg + c1;
        lcur[2 * t + 1] = beg;
    }
    __syncthreads();
    for (int e = regbeg + t; e < regend; e += 256) {
        unsigned p = ebuf[e];
        int slot = atomicAdd(&lcur[p >> pay_sh], 1);
        adj[slot] = (int)(p & pmask);
    }
}

// ---------------- gather u+i in one launch ----------------
__global__ __launch_bounds__(256) void gather_all(
    const short* __restrict__ embU, const short* __restrict__ embI,
    const int* __restrict__ off_u, const int* __restrict__ end_u, const int* __restrict__ adj_u,
    const int* __restrict__ off_i, const int* __restrict__ end_i, const int* __restrict__ adj_i,
    short* __restrict__ nub, short* __restrict__ nib, int U, int I)
{
    int gw = (blockIdx.x * 256 + threadIdx.x) >> 6;
    int lane = threadIdx.x & 63;
    const short* emb; const int *offp, *endp, *adjp; short* outp; int row;
    if (gw < U)          { emb = embU; offp = off_u; endp = end_u; adjp = adj_u; outp = nub; row = gw; }
    else if (gw < U + I) { emb = embI; offp = off_i; endp = end_i; adjp = adj_i; outp = nib; row = gw - U; }
    else return;

    int beg = offp[row], end = endp[row];
    float ax = 0.f, ay = 0.f;
    int j = beg;
    for (; j + 3 < end; j += 4) {
        unsigned a = *(const unsigned*)(emb + (size_t)adjp[j]     * D_ + lane * 2);
        unsigned b = *(const unsigned*)(emb + (size_t)adjp[j + 1] * D_ + lane * 2);
        unsigned c = *(const unsigned*)(emb + (size_t)adjp[j + 2] * D_ + lane * 2);
        unsigned d = *(const unsigned*)(emb + (size_t)adjp[j + 3] * D_ + lane * 2);
        ax += b2f((short)(a & 0xffff)) + b2f((short)(b & 0xffff))
            + b2f((short)(c & 0xffff)) + b2f((short)(d & 0xffff));
        ay += b2f((short)(a >> 16)) + b2f((short)(b >> 16))
            + b2f((short)(c >> 16)) + b2f((short)(d >> 16));
    }
    for (; j < end; ++j) {
        unsigned a = *(const unsigned*)(emb + (size_t)adjp[j] * D_ + lane * 2);
        ax += b2f((short)(a & 0xffff));
        ay += b2f((short)(a >> 16));
    }
    unsigned o = ((unsigned)(unsigned short)f2b(ay) << 16) | (unsigned short)(unsigned)f2b(ax);
    *(unsigned*)(outp + (size_t)row * D_ + lane * 2) = o;
}

// ---------------- fused gemm + MLP + norm; y->bf16; per-block colsum partial ----------------
// (round-7 best-measured configuration + T5 s_setprio around MFMA clusters)
struct MlpArgs {
    const short *uA0, *uA1, *uA2, *uA3;
    const short *iA0, *iA1;
    const short *uWg, *uW1, *uW2, *uW3;
    const short *iWg, *iW1, *iW2, *iW3;
    const float *ubg, *ub1, *ub2, *ub3;
    const float *ibg, *ib1, *ib2, *ib3;
    short *uY, *iY;
    float *uPart, *iPart;
    int UB;
};

__global__ __launch_bounds__(256, 3) void fused_mlp_all(MlpArgs P)
{
    __shared__ char pool[47104];
    __shared__ float wred[4][16];
    __shared__ float nrms[16];

    short* x2 = (short*)pool;
    short* xc = (short*)(pool + 4096);
    short* h1 = (short*)(pool + 4096);
    short* h2 = (short*)(pool + 45056);
    short* yb = (short*)pool;

    const int t = threadIdx.x;
    const int l = t & 63;
    const int w = t >> 6;
    const int lr = l & 15;
    const int lg = l >> 4;

    const bool isU = (int)blockIdx.x < P.UB;
    const int bid = isU ? (int)blockIdx.x : (int)blockIdx.x - P.UB;
    const size_t rb0 = (size_t)bid * 16;
    const int CHSH = isU ? 6 : 5;           // log2(KCAT/8)
    const int KKG  = isU ? 16 : 8;          // KCAT/32
    const short* Wg = isU ? P.uWg : P.iWg;
    const short* W1 = isU ? P.uW1 : P.iW1;
    const short* W2 = isU ? P.uW2 : P.iW2;
    const short* W3 = isU ? P.uW3 : P.iW3;
    const float* bg = isU ? P.ubg : P.ibg;
    const float* b1 = isU ? P.ub1 : P.ib1;
    const float* b2 = isU ? P.ub2 : P.ib2;
    const float* b3 = isU ? P.ub3 : P.ib3;
    short* Ybf = isU ? P.uY : P.iY;
    float* part = (isU ? P.uPart : P.iPart) + (size_t)bid * DK_;

    // ---- stage concat-x into LDS (swizzled 16B slots) ----
    const int CH_ROW = 1 << CHSH;
    for (int idx = t; idx < (16 << CHSH); idx += 256) {
        int row = idx >> CHSH;
        int slot = idx & (CH_ROW - 1);
        int a = slot >> 4, cs = slot & 15;
        const short* src = isU ? (a == 0 ? P.uA0 : a == 1 ? P.uA1 : a == 2 ? P.uA2 : P.uA3)
                               : (a == 0 ? P.iA0 : P.iA1);
        bh8 v = *(const bh8*)(src + (rb0 + row) * D_ + cs * 8);
        int sl2 = slot ^ (row & 7);
        *(bh8*)(xc + (row << (CHSH + 3)) + sl2 * 8) = v;
    }
    __syncthreads();

    // ---- gemm: tmp = xcat @ Wg + bg -> x2 (bf16) ----
    {
        f32x4 accA0 = {0,0,0,0}, accB0 = accA0, accA1 = accA0, accB1 = accA0;
        __builtin_amdgcn_s_setprio(1);
#pragma unroll 4
        for (int kk = 0; kk < KKG; ++kk) {
            int slot = kk * 4 + lg;
            bh8 af = *(const bh8*)(xc + (lr << (CHSH + 3)) + ((slot ^ (lr & 7)) * 8));
            bh8 b0 = *(const bh8*)(Wg + (((size_t)(2 * w) * KKG + kk) * 64 + l) * 8);
            bh8 b1v = *(const bh8*)(Wg + (((size_t)(2 * w + 1) * KKG + kk) * 64 + l) * 8);
            if (kk & 1) { accB0 = mfma16(af, b0, accB0); accB1 = mfma16(af, b1v, accB1); }
            else        { accA0 = mfma16(af, b0, accA0); accA1 = mfma16(af, b1v, accA1); }
        }
        __builtin_amdgcn_s_setprio(0);
#pragma unroll
        for (int r = 0; r < 4; ++r) {
            int row = lg * 4 + r;
            int c0 = (2 * w) * 16 + lr;
            int c1 = c0 + 16;
            x2[row * 128 + (((c0 >> 3) ^ (row & 7)) * 8) + (l & 7)] = f2b(accA0[r] + accB0[r] + bg[c0]);
            x2[row * 128 + (((c1 >> 3) ^ (row & 7)) * 8) + (l & 7)] = f2b(accA1[r] + accB1[r] + bg[c1]);
        }
    }
    __syncthreads();

    // ---- phase 1: h1 = tanh(x2 @ W1 + b1) ----
    {
        bh8 a1f[4];
#pragma unroll
        for (int kk = 0; kk < 4; ++kk) {
            int slot = kk * 4 + lg;
            a1f[kk] = *(const bh8*)(x2 + lr * 128 + (slot ^ (lr & 7)) * 8);
        }
#pragma unroll 2
        for (int tile = w * 20; tile < w * 20 + 20; ++tile) {
            float bv = b1[tile * 16 + lr];
            f32x4 acc = {bv, bv, bv, bv};
            __builtin_amdgcn_s_setprio(1);
#pragma unroll
            for (int kk = 0; kk < 4; ++kk) {
                bh8 bf_ = *(const bh8*)(W1 + (((size_t)tile * 4 + kk) * 64 + l) * 8);
                acc = mfma16(a1f[kk], bf_, acc);
            }
            __builtin_amdgcn_s_setprio(0);
#pragma unroll
            for (int r = 0; r < 4; ++r) {
                int row = lg * 4 + r;
                int col = tile * 16 + lr;
                h1[row * 1280 + (((col >> 3) ^ (row & 7)) * 8) + (l & 7)] = f2b(tanh_fast(acc[r]));
            }
        }
    }
    __syncthreads();

    // ---- phase 2: h2 = tanh(h1 @ W2 + b2) ----
    {
        float bv = b2[w * 16 + lr];
        f32x4 accA = {bv, bv, bv, bv}, accB = {0,0,0,0};
        __builtin_amdgcn_s_setprio(1);
#pragma unroll 4
        for (int kk = 0; kk < 40; ++kk) {
            int slot = kk * 4 + lg;
            bh8 af = *(const bh8*)(h1 + lr * 1280 + (slot ^ (lr & 7)) * 8);
            bh8 bf_ = *(const bh8*)(W2 + (((size_t)w * 40 + kk) * 64 + l) * 8);
            if (kk & 1) accB = mfma16(af, bf_, accB);
            else        accA = mfma16(af, bf_, accA);
        }
        __builtin_amdgcn_s_setprio(0);
#pragma unroll
        for (int r = 0; r < 4; ++r) {
            int row = lg * 4 + r;
            int col = w * 16 + lr;
            h2[row * 64 + (((col >> 3) ^ (row & 7)) * 8) + (l & 7)] = f2b(tanh_fast(accA[r] + accB[r]));
        }
    }
    __syncthreads();

    // ---- phase 3: y = h2 @ W3 + b3 -> ybuf(bf16), ssq ----
    {
        bh8 a3[2];
#pragma unroll
        for (int kk = 0; kk < 2; ++kk) {
            int slot = kk * 4 + lg;
            a3[kk] = *(const bh8*)(h2 + lr * 64 + (slot ^ (lr & 7)) * 8);
        }
        float ssq[4] = {0.f, 0.f, 0.f, 0.f};
#pragma unroll 2
        for (int tile = w * 20; tile < w * 20 + 20; ++tile) {
            float bv = b3[tile * 16 + lr];
            f32x4 acc = {bv, bv, bv, bv};
            bh8 b0 = *(const bh8*)(W3 + (((size_t)tile * 2 + 0) * 64 + l) * 8);
            bh8 b1v = *(const bh8*)(W3 + (((size_t)tile * 2 + 1) * 64 + l) * 8);
            __builtin_amdgcn_s_setprio(1);
            acc = mfma16(a3[0], b0, acc);
            acc = mfma16(a3[1], b1v, acc);
            __builtin_amdgcn_s_setprio(0);
            bh4 pk;
#pragma unroll
            for (int r = 0; r < 4; ++r) {
                ssq[r] = fmaf(acc[r], acc[r], ssq[r]);
                pk[r] = f2b(acc[r]);
            }
            *(bh4*)(yb + tile * 260 + l * 4) = pk;
        }
#pragma unroll
        for (int off = 1; off < 16; off <<= 1) {
#pragma unroll
            for (int r = 0; r < 4; ++r) ssq[r] += __shfl_xor(ssq[r], off);
        }
        if (lr == 0) {
#pragma unroll
            for (int r = 0; r < 4; ++r) wred[w][lg * 4 + r] = ssq[r];
        }
    }
    __syncthreads();
    if (t < 16) {
        float s = wred[0][t] + wred[1][t] + wred[2][t] + wred[3][t];
        nrms[t] = 1.f / fmaxf(sqrtf(s), 1e-12f);
    }
    __syncthreads();

    // ---- writeout: normalized bf16; per-block colsum partial (non-atomic) ----
    {
        float csum[5] = {0.f, 0.f, 0.f, 0.f, 0.f};
        for (int row = 0; row < 16; ++row) {
            float nv = nrms[row];
            int lph = (row >> 2) << 4;
            int r = row & 3;
#pragma unroll
            for (int ch = 0; ch < 5; ++ch) {
                int c = ch * 256 + t;
                int tile = c >> 4;
                int lanep = lph | (c & 15);
                float v = b2f(yb[tile * 260 + lanep * 4 + r]) * nv;
                Ybf[(rb0 + row) * DK_ + c] = f2b(v);
                csum[ch] += v;
            }
        }
#pragma unroll
        for (int ch = 0; ch < 5; ++ch) part[ch * 256 + t] = csum[ch];
    }
}

// ---------------- reduce per-block colsum partials -> bsu/bsi ----------------
__global__ __launch_bounds__(256) void finalize_bias(
    const float* __restrict__ partU, const float* __restrict__ partI,
    float* __restrict__ bsu, float* __restrict__ bsi, int NU, int NI)
{
    int c = blockIdx.x * 256 + threadIdx.x;     // grid.x = 5 -> c < 1280
    int z = blockIdx.z;
    const float* part = z ? partI : partU;
    float* dst = z ? bsi : bsu;
    int M = z ? NI : NU;
    int chunk = (M + gridDim.y - 1) / gridDim.y;
    int r0 = blockIdx.y * chunk;
    int r1 = min(M, r0 + chunk);
    if (r0 >= r1) return;
    float s = 0.f;
    for (int r = r0; r < r1; ++r) s += part[(size_t)r * DK_ + c];
    atomicAdd(&dst[c], s);
}

// ---------------- softmax u (over D, stride K) + i (over K, stride D), one launch ----------------
__global__ __launch_bounds__(64) void softmax_all(
    const short* __restrict__ Yu, const short* __restrict__ Yi,
    const float* __restrict__ bsu, const float* __restrict__ bsi,
    float invU, float invI,
    float* __restrict__ outu, float* __restrict__ outi, int U, int I)
{
    __shared__ float rowb[DK_];
    int b = blockIdx.x;
    int t = threadIdx.x;
    if (b < U) {
        size_t base = (size_t)b * DK_;
        for (int i = t; i < DK_ / 4; i += 64) {
            uint2 a = ((const uint2*)(Yu + base))[i];
            float4 bv = ((const float4*)bsu)[i];
            rowb[4 * i + 0] = b2f((short)(a.x & 0xffff)) + bv.x * invU;
            rowb[4 * i + 1] = b2f((short)(a.x >> 16))    + bv.y * invU;
            rowb[4 * i + 2] = b2f((short)(a.y & 0xffff)) + bv.z * invU;
            rowb[4 * i + 3] = b2f((short)(a.y >> 16))    + bv.w * invU;
        }
        __syncthreads();
#pragma unroll 1
        for (int k = 0; k < K_; ++k) {
            float v0 = rowb[t * K_ + k];
            float v1 = rowb[(t + 64) * K_ + k];
            float m = fmaxf(v0, v1);
            for (int off = 32; off; off >>= 1) m = fmaxf(m, __shfl_xor(m, off));
            float e0 = expf(v0 - m), e1 = expf(v1 - m);
            float s = e0 + e1;
            for (int off = 32; off; off >>= 1) s += __shfl_xor(s, off);
            float rs = 1.f / s;
            rowb[t * K_ + k] = e0 * rs;
            rowb[(t + 64) * K_ + k] = e1 * rs;
        }
        __syncthreads();
        for (int i = t; i < DK_ / 4; i += 64)
            ((float4*)(outu + base))[i] = ((const float4*)rowb)[i];
    } else {
        int it = b - U;
        if (it >= I) return;
        size_t base = (size_t)it * DK_;
        float v0[K_], v1[K_];
        float m0 = -1e30f, m1 = -1e30f;
#pragma unroll
        for (int k = 0; k < K_; ++k) {
            unsigned a = *(const unsigned*)(Yi + base + k * D_ + 2 * t);
            float2 bv = ((const float2*)(bsi + k * D_))[t];
            v0[k] = b2f((short)(a & 0xffff)) + bv.x * invI;
            v1[k] = b2f((short)(a >> 16))    + bv.y * invI;
            m0 = fmaxf(m0, v0[k]); m1 = fmaxf(m1, v1[k]);
        }
        float s0 = 0.f, s1 = 0.f;
#pragma unroll
        for (int k = 0; k < K_; ++k) {
            v0[k] = expf(v0[k] - m0); s0 += v0[k];
            v1[k] = expf(v1[k] - m1); s1 += v1[k];
        }
        float r0 = 1.f / s0, r1 = 1.f / s1;
#pragma unroll
        for (int k = 0; k < K_; ++k) {
            float2 o; o.x = v0[k] * r0; o.y = v1[k] * r1;
            ((float2*)(outi + base + k * D_))[t] = o;
        }
    }
}

extern "C" void kernel_launch(void* const* d_in, const int* in_sizes, int n_in,
                              void* d_out, int out_size, void* d_ws, size_t ws_size,
                              hipStream_t stream)
{
    const float* uemb_s   = (const float*)d_in[0];
    const float* iemb_s   = (const float*)d_in[1];
    const float* uemb_t   = (const float*)d_in[2];
    const float* u_emb_sp = (const float*)d_in[3];
    const int*   eu       = (const int*)d_in[4];
    const int*   ei       = (const int*)d_in[5];
    const float* Wu  = (const float*)d_in[6];
    const float* bu  = (const float*)d_in[7];
    const float* Wi  = (const float*)d_in[8];
    const float* bi  = (const float*)d_in[9];
    const float* m1w1 = (const float*)d_in[10];
    const float* m1b1 = (const float*)d_in[11];
    const float* m1w2 = (const float*)d_in[12];
    const float* m1b2 = (const float*)d_in[13];
    const float* m1w3 = (const float*)d_in[14];
    const float* m1b3 = (const float*)d_in[15];
    const float* m2w1 = (const float*)d_in[16];
    const float* m2b1 = (const float*)d_in[17];
    const float* m2w2 = (const float*)d_in[18];
    const float* m2b2 = (const float*)d_in[19];
    const float* m2w3 = (const float*)d_in[20];
    const float* m2b3 = (const float*)d_in[21];

    const int U = in_sizes[0] / D_;
    const int I = in_sizes[1] / D_;
    const int E = in_sizes[4];

    const int SHU = 9, SHI = 8;
    const int NBU = (U + 511) >> 9;
    const int NBI = (I + 255) >> 8;
    const int UB = U / 16, IB = I / 16;

    char* p = (char*)d_ws;
    auto alloc = [&](size_t bytes) { char* r = p; p += (bytes + 255) & ~(size_t)255; return r; };

    short* usb  = (short*)alloc((size_t)U * D_ * 2);
    short* utb  = (short*)alloc((size_t)U * D_ * 2);
    short* uspb = (short*)alloc((size_t)U * D_ * 2);
    short* uavg = (short*)alloc((size_t)U * D_ * 2);
    short* isb  = (short*)alloc((size_t)I * D_ * 2);
    short* nub  = (short*)alloc((size_t)U * D_ * 2);
    short* nib  = (short*)alloc((size_t)I * D_ * 2);
    short* ybu  = (short*)alloc((size_t)U * DK_ * 2);
    short* ybi  = (short*)alloc((size_t)I * DK_ * 2);
    float* partU = (float*)alloc((size_t)UB * DK_ * 4);
    float* partI = (float*)alloc((size_t)IB * DK_ * 4);
    short* WgU  = (short*)alloc(512 * 128 * 2);
    short* WgI  = (short*)alloc(256 * 128 * 2);
    short* W1U  = (short*)alloc(128 * 1280 * 2);
    short* W2U  = (short*)alloc(1280 * 64 * 2);
    short* W3U  = (short*)alloc(64 * 1280 * 2);
    short* W1I  = (short*)alloc(128 * 1280 * 2);
    short* W2I  = (short*)alloc(1280 * 64 * 2);
    short* W3I  = (short*)alloc(64 * 1280 * 2);
    int*   zbuf = (int*)alloc((320 + 2 * DK_) * 4);    // bcnt | bsu | bsi, one memset
    int* bcnt_u = zbuf;
    int* bcnt_i = zbuf + 160;
    float* bsu  = (float*)(zbuf + 320);
    float* bsi  = bsu + DK_;
    int* gcur_u = (int*)alloc(160 * 4);
    int* gcur_i = (int*)alloc(160 * 4);
    int* bbase_u = (int*)alloc(161 * 4);
    int* bbase_i = (int*)alloc(161 * 4);
    int* off_u  = (int*)alloc((size_t)U * 4);
    int* end_u  = (int*)alloc((size_t)U * 4);
    int* off_i  = (int*)alloc((size_t)I * 4);
    int* end_i  = (int*)alloc((size_t)I * 4);
    unsigned* ebu = (unsigned*)alloc((size_t)E * 4);
    unsigned* ebi = (unsigned*)alloc((size_t)E * 4);
    int* adj_u  = (int*)alloc((size_t)E * 4);
    int* adj_i  = (int*)alloc((size_t)E * 4);

    float* outu = (float*)d_out;
    float* outi = outu + (size_t)U * DK_;

    hipMemsetAsync(zbuf, 0, (320 + 2 * DK_) * 4, stream);

    int n4u = U * D_ / 4, n4i = I * D_ / 4;
    cvt_all<<<(n4u + n4i + 255) / 256, 256, 0, stream>>>(
        uemb_s, uemb_t, u_emb_sp, iemb_s, usb, utb, uspb, uavg, isb, n4u, n4i);

    PackArgs pa;
    pa.W[0] = Wu;   pa.o[0] = WgU; pa.K[0] = 512;  pa.N[0] = 128;
    pa.W[1] = Wi;   pa.o[1] = WgI; pa.K[1] = 256;  pa.N[1] = 128;
    pa.W[2] = m1w1; pa.o[2] = W1U; pa.K[2] = 128;  pa.N[2] = 1280;
    pa.W[3] = m1w2; pa.o[3] = W2U; pa.K[3] = 1280; pa.N[3] = 64;
    pa.W[4] = m1w3; pa.o[4] = W3U; pa.K[4] = 64;   pa.N[4] = 1280;
    pa.W[5] = m2w1; pa.o[5] = W1I; pa.K[5] = 128;  pa.N[5] = 1280;
    pa.W[6] = m2w2; pa.o[6] = W2I; pa.K[6] = 1280; pa.N[6] = 64;
    pa.W[7] = m2w3; pa.o[7] = W3I; pa.K[7] = 64;   pa.N[7] = 1280;
    pack_all<<<dim3(640, 8), 256, 0, stream>>>(pa);

    int pb = (E + 4095) / 4096;
    bhist_kernel<<<pb, 256, 0, stream>>>(eu, ei, bcnt_u, bcnt_i, E, SHU, SHI, NBU, NBI);
    binit_kernel<<<1, 256, 0, stream>>>(bcnt_u, gcur_u, bbase_u, NBU,
                                        bcnt_i, gcur_i, bbase_i, NBI, E);
    partition_kernel<<<pb, 256, 0, stream>>>(eu, ei, gcur_u, gcur_i, ebu, ebi,
                                             E, SHU, SHI, NBU, NBI);
    fill2_all<<<NBU + NBI, 256, 0, stream>>>(ebu, bbase_u, off_u, end_u, adj_u, NBU, U,
                                             ebi, bbase_i, off_i, end_i, adj_i, I);

    gather_all<<<(U + I + 3) / 4, 256, 0, stream>>>(
        isb, uavg, off_u, end_u, adj_u, off_i, end_i, adj_i, nub, nib, U, I);

    MlpArgs ma;
    ma.uA0 = usb; ma.uA1 = utb; ma.uA2 = uspb; ma.uA3 = nub;
    ma.iA0 = isb; ma.iA1 = nib;
    ma.uWg = WgU; ma.uW1 = W1U; ma.uW2 = W2U; ma.uW3 = W3U;
    ma.iWg = WgI; ma.iW1 = W1I; ma.iW2 = W2I; ma.iW3 = W3I;
    ma.ubg = bu; ma.ub1 = m1b1; ma.ub2 = m1b2; ma.ub3 = m1b3;
    ma.ibg = bi; ma.ib1 = m2b1; ma.ib2 = m2b2; ma.ib3 = m2b3;
    ma.uY = ybu; ma.iY = ybi;
    ma.uPart = partU; ma.iPart = partI;
    ma.UB = UB;
    fused_mlp_all<<<UB + IB, 256, 0, stream>>>(ma);

    finalize_bias<<<dim3(5, 40, 2), 256, 0, stream>>>(partU, partI, bsu, bsi, UB, IB);

    softmax_all<<<U + I, 64, 0, stream>>>(ybu, ybi, bsu, bsi,
                                          1.0f / (float)U, 1.0f / (float)I, outu, outi, U, I);
}

// Round 17
// 878.794 us; speedup vs baseline: 1.1121x; 1.1121x over previous
//
#include <hip/hip_runtime.h>
#include <hip/hip_bf16.h>

#define D_ 128
#define DK_ 1280
#define K_ 10

typedef __attribute__((ext_vector_type(8))) short bh8;   // 8 bf16 = 4 VGPR (MFMA A/B frag)
typedef __attribute__((ext_vector_type(4))) short bh4;
typedef __attribute__((ext_vector_type(4))) float f32x4; // MFMA C/D frag

__device__ __forceinline__ short f2b(float f) {
    unsigned u = __builtin_bit_cast(unsigned, f);
    u += 0x7fffu + ((u >> 16) & 1u);          // RNE
    return (short)(u >> 16);
}
__device__ __forceinline__ float b2f(short s) {
    unsigned u = ((unsigned)(unsigned short)s) << 16;
    return __builtin_bit_cast(float, u);
}
__device__ __forceinline__ float tanh_fast(float x) {
    float e = __expf(2.f * x);
    return 1.f - __fdividef(2.f, e + 1.f);
}
__device__ __forceinline__ f32x4 mfma16(bh8 a, bh8 b, f32x4 c) {
    return __builtin_amdgcn_mfma_f32_16x16x32_bf16(a, b, c, 0, 0, 0);
}

// block-exclusive scan of one int per thread (256 threads)
__device__ __forceinline__ int blk_excl_scan(int v, int t) {
    __shared__ int wp[4];
    int lane = t & 63, w = t >> 6;
    int s = v;
    for (int o = 1; o < 64; o <<= 1) {
        int pv = __shfl_up(s, o);
        if (lane >= o) s += pv;
    }
    if (lane == 63) wp[w] = s;
    __syncthreads();
    if (t == 0) {
        int a = 0;
#pragma unroll
        for (int k = 0; k < 4; ++k) { int x = wp[k]; wp[k] = a; a += x; }
    }
    __syncthreads();
    int r = s - v + wp[w];
    __syncthreads();
    return r;
}

// ---------------- fused f32->bf16 conversions + uavg ----------------
__global__ __launch_bounds__(256) void cvt_all(
    const float* __restrict__ us, const float* __restrict__ ut,
    const float* __restrict__ usp, const float* __restrict__ is_,
    short* __restrict__ usb, short* __restrict__ utb,
    short* __restrict__ uspb, short* __restrict__ uavg, short* __restrict__ isb,
    int n4u, int n4i)
{
    int i = blockIdx.x * 256 + threadIdx.x;
    if (i < n4u) {
        float4 a = ((const float4*)us)[i];
        float4 b = ((const float4*)ut)[i];
        float4 c = ((const float4*)usp)[i];
        bh4 sa, sb, sc, sv;
        sa[0] = f2b(a.x); sa[1] = f2b(a.y); sa[2] = f2b(a.z); sa[3] = f2b(a.w);
        sb[0] = f2b(b.x); sb[1] = f2b(b.y); sb[2] = f2b(b.z); sb[3] = f2b(b.w);
        sc[0] = f2b(c.x); sc[1] = f2b(c.y); sc[2] = f2b(c.z); sc[3] = f2b(c.w);
        sv[0] = f2b(0.5f * (a.x + c.x)); sv[1] = f2b(0.5f * (a.y + c.y));
        sv[2] = f2b(0.5f * (a.z + c.z)); sv[3] = f2b(0.5f * (a.w + c.w));
        ((bh4*)usb)[i] = sa; ((bh4*)utb)[i] = sb;
        ((bh4*)uspb)[i] = sc; ((bh4*)uavg)[i] = sv;
    } else if (i < n4u + n4i) {
        int j = i - n4u;
        float4 v = ((const float4*)is_)[j];
        bh4 s;
        s[0] = f2b(v.x); s[1] = f2b(v.y); s[2] = f2b(v.z); s[3] = f2b(v.w);
        ((bh4*)isb)[j] = s;
    }
}

// ---------------- pack all weights: W[K][N] f32 -> bf16 MFMA-fragment order ----------------
struct PackArgs {
    const float* W[8];
    short* o[8];
    int K[8];
    int N[8];
};
__global__ __launch_bounds__(256) void pack_all(PackArgs pa)
{
    int seg = blockIdx.y;
    int K = pa.K[seg], N = pa.N[seg];
    int total = K * N;
    int o = blockIdx.x * 256 + threadIdx.x;
    if (o >= total) return;
    const float* W = pa.W[seg];
    short* out = pa.o[seg];
    int j    = o & 7;
    int lane = (o >> 3) & 63;
    int rest = o >> 9;
    int KK = K >> 5;
    int kk = rest % KK;
    int tile = rest / KK;
    int k = kk * 32 + (lane >> 4) * 8 + j;
    int n = tile * 16 + (lane & 15);
    out[o] = f2b(W[(size_t)k * N + n]);
}

// ---------------- CSR build: bucket histogram (LDS-aggregated) ----------------
__global__ __launch_bounds__(256) void bhist_kernel(
    const int* __restrict__ eu, const int* __restrict__ ei,
    int* __restrict__ bcu, int* __restrict__ bci,
    int E, int shu, int shi, int nbu, int nbi)
{
    __shared__ int hu[160], hi[160];
    int t = threadIdx.x;
    int base = blockIdx.x * 4096;
    if (t < 160) { hu[t] = 0; hi[t] = 0; }
    __syncthreads();
    int n = min(4096, E - base);
#pragma unroll 4
    for (int k = 0; k < 16; ++k) {
        int idx = k * 256 + t;
        if (idx < n) {
            atomicAdd(&hu[eu[base + idx] >> shu], 1);
            atomicAdd(&hi[ei[base + idx] >> shi], 1);
        }
    }
    __syncthreads();
    if (t < nbu && hu[t]) atomicAdd(&bcu[t], hu[t]);
    if (t < nbi && hi[t]) atomicAdd(&bci[t], hi[t]);
}

// ---------------- CSR build: bucket base scan ----------------
__global__ __launch_bounds__(256) void binit_kernel(
    const int* __restrict__ bcu, int* __restrict__ gcu, int* __restrict__ bbu, int nbu,
    const int* __restrict__ bci, int* __restrict__ gci, int* __restrict__ bbi, int nbi,
    int E)
{
    int t = threadIdx.x;
    {
        int v = (t < nbu) ? bcu[t] : 0;
        int ex = blk_excl_scan(v, t);
        if (t < nbu) { gcu[t] = ex; bbu[t] = ex; }
        if (t == 0) bbu[nbu] = E;
    }
    __syncthreads();
    {
        int v = (t < nbi) ? bci[t] : 0;
        int ex = blk_excl_scan(v, t);
        if (t < nbi) { gci[t] = ex; bbi[t] = ex; }
        if (t == 0) bbi[nbi] = E;
    }
}

// ---------------- CSR build: partition edges into buckets (4B packed entries) ----------------
// u-side entry: (u&511)<<16 | item   (item < 65536)
// i-side entry: (i&255)<<17 | user   (user < 131072)
__global__ __launch_bounds__(256) void partition_kernel(
    const int* __restrict__ eu, const int* __restrict__ ei,
    int* __restrict__ gcu, int* __restrict__ gci,
    unsigned* __restrict__ ebu, unsigned* __restrict__ ebi,
    int E, int shu, int shi, int nbu, int nbi)
{
    __shared__ int hu[160], hi[160];
    int t = threadIdx.x;
    int base = blockIdx.x * 4096;
    if (t < 160) { hu[t] = 0; hi[t] = 0; }
    __syncthreads();
    int n = min(4096, E - base);
    int us[16], is_[16];
#pragma unroll 4
    for (int k = 0; k < 16; ++k) {
        int idx = k * 256 + t;
        if (idx < n) {
            us[k] = eu[base + idx];
            is_[k] = ei[base + idx];
            atomicAdd(&hu[us[k] >> shu], 1);
            atomicAdd(&hi[is_[k] >> shi], 1);
        } else us[k] = -1;
    }
    __syncthreads();
    if (t < nbu) { int c = hu[t]; hu[t] = c ? atomicAdd(&gcu[t], c) : 0; }
    if (t < nbi) { int c = hi[t]; hi[t] = c ? atomicAdd(&gci[t], c) : 0; }
    __syncthreads();
#pragma unroll 4
    for (int k = 0; k < 16; ++k) {
        if (us[k] >= 0) {
            int p1 = atomicAdd(&hu[us[k] >> shu], 1);
            ebu[p1] = ((unsigned)(us[k] & 511) << 16) | (unsigned)is_[k];
            int p2 = atomicAdd(&hi[is_[k] >> shi], 1);
            ebi[p2] = ((unsigned)(is_[k] & 255) << 17) | (unsigned)us[k];
        }
    }
}

// ---------------- CSR build: per-bucket offsets + adjacency (u and i sides) ----------------
__global__ __launch_bounds__(256) void fill2_all(
    const unsigned* __restrict__ ebu, const int* __restrict__ bbu,
    int* __restrict__ off_u, int* __restrict__ end_u, int* __restrict__ adj_u,
    int NBU, int U,
    const unsigned* __restrict__ ebi, const int* __restrict__ bbi,
    int* __restrict__ off_i, int* __restrict__ end_i, int* __restrict__ adj_i, int I)
{
    __shared__ int lcnt[512];
    __shared__ int lcur[512];
    bool isU = (int)blockIdx.x < NBU;
    const unsigned* ebuf = isU ? ebu : ebi;
    const int* bbase  = isU ? bbu : bbi;
    int* off  = isU ? off_u : off_i;
    int* end_ = isU ? end_u : end_i;
    int* adj  = isU ? adj_u : adj_i;
    int span_sh = isU ? 9 : 8;
    int pay_sh = isU ? 16 : 17;
    unsigned pmask = (1u << pay_sh) - 1u;
    int nrows = isU ? U : I;
    int b = isU ? blockIdx.x : blockIdx.x - NBU;

    int t = threadIdx.x;
    int rbase = b << span_sh;
    int span = min(1 << span_sh, nrows - rbase);
    int regbeg = bbase[b], regend = bbase[b + 1];
    for (int j = t; j < span; j += 256) lcnt[j] = 0;
    __syncthreads();
    for (int e = regbeg + t; e < regend; e += 256)
        atomicAdd(&lcnt[ebuf[e] >> pay_sh], 1);
    __syncthreads();
    int c0 = (2 * t < span) ? lcnt[2 * t] : 0;
    int c1 = (2 * t + 1 < span) ? lcnt[2 * t + 1] : 0;
    int ex = blk_excl_scan(c0 + c1, t);
    if (2 * t < span) {
        int beg = regbeg + ex;
        off[rbase + 2 * t] = beg;
        end_[rbase + 2 * t] = beg + c0;
        lcur[2 * t] = beg;
    }
    if (2 * t + 1 < span) {
        int beg = regbeg + ex + c0;
        off[rbase + 2 * t + 1] = beg;
        end_[rbase + 2 * t + 1] = beg + c1;
        lcur[2 * t + 1] = beg;
    }
    __syncthreads();
    for (int e = regbeg + t; e < regend; e += 256) {
        unsigned p = ebuf[e];
        int slot = atomicAdd(&lcur[p >> pay_sh], 1);
        adj[slot] = (int)(p & pmask);
    }
}

// ---------------- gather u+i in one launch ----------------
__global__ __launch_bounds__(256) void gather_all(
    const short* __restrict__ embU, const short* __restrict__ embI,
    const int* __restrict__ off_u, const int* __restrict__ end_u, const int* __restrict__ adj_u,
    const int* __restrict__ off_i, const int* __restrict__ end_i, const int* __restrict__ adj_i,
    short* __restrict__ nub, short* __restrict__ nib, int U, int I)
{
    int gw = (blockIdx.x * 256 + threadIdx.x) >> 6;
    int lane = threadIdx.x & 63;
    const short* emb; const int *offp, *endp, *adjp; short* outp; int row;
    if (gw < U)          { emb = embU; offp = off_u; endp = end_u; adjp = adj_u; outp = nub; row = gw; }
    else if (gw < U + I) { emb = embI; offp = off_i; endp = end_i; adjp = adj_i; outp = nib; row = gw - U; }
    else return;

    int beg = offp[row], end = endp[row];
    float ax = 0.f, ay = 0.f;
    int j = beg;
    for (; j + 3 < end; j += 4) {
        unsigned a = *(const unsigned*)(emb + (size_t)adjp[j]     * D_ + lane * 2);
        unsigned b = *(const unsigned*)(emb + (size_t)adjp[j + 1] * D_ + lane * 2);
        unsigned c = *(const unsigned*)(emb + (size_t)adjp[j + 2] * D_ + lane * 2);
        unsigned d = *(const unsigned*)(emb + (size_t)adjp[j + 3] * D_ + lane * 2);
        ax += b2f((short)(a & 0xffff)) + b2f((short)(b & 0xffff))
            + b2f((short)(c & 0xffff)) + b2f((short)(d & 0xffff));
        ay += b2f((short)(a >> 16)) + b2f((short)(b >> 16))
            + b2f((short)(c >> 16)) + b2f((short)(d >> 16));
    }
    for (; j < end; ++j) {
        unsigned a = *(const unsigned*)(emb + (size_t)adjp[j] * D_ + lane * 2);
        ax += b2f((short)(a & 0xffff));
        ay += b2f((short)(a >> 16));
    }
    unsigned o = ((unsigned)(unsigned short)f2b(ay) << 16) | (unsigned short)(unsigned)f2b(ax);
    *(unsigned*)(outp + (size_t)row * D_ + lane * 2) = o;
}

// ---------------- fused gemm + MLP + norm; y->bf16; per-block colsum partial ----------------
// (round-7 best-measured configuration: 16 rows/block, XOR-swizzled LDS, ~371 us)
struct MlpArgs {
    const short *uA0, *uA1, *uA2, *uA3;
    const short *iA0, *iA1;
    const short *uWg, *uW1, *uW2, *uW3;
    const short *iWg, *iW1, *iW2, *iW3;
    const float *ubg, *ub1, *ub2, *ub3;
    const float *ibg, *ib1, *ib2, *ib3;
    short *uY, *iY;
    float *uPart, *iPart;
    int UB;
};

__global__ __launch_bounds__(256, 3) void fused_mlp_all(MlpArgs P)
{
    __shared__ char pool[47104];
    __shared__ float wred[4][16];
    __shared__ float nrms[16];

    short* x2 = (short*)pool;
    short* xc = (short*)(pool + 4096);
    short* h1 = (short*)(pool + 4096);
    short* h2 = (short*)(pool + 45056);
    short* yb = (short*)pool;

    const int t = threadIdx.x;
    const int l = t & 63;
    const int w = t >> 6;
    const int lr = l & 15;
    const int lg = l >> 4;

    const bool isU = (int)blockIdx.x < P.UB;
    const int bid = isU ? (int)blockIdx.x : (int)blockIdx.x - P.UB;
    const size_t rb0 = (size_t)bid * 16;
    const int CHSH = isU ? 6 : 5;           // log2(KCAT/8)
    const int KKG  = isU ? 16 : 8;          // KCAT/32
    const short* Wg = isU ? P.uWg : P.iWg;
    const short* W1 = isU ? P.uW1 : P.iW1;
    const short* W2 = isU ? P.uW2 : P.iW2;
    const short* W3 = isU ? P.uW3 : P.iW3;
    const float* bg = isU ? P.ubg : P.ibg;
    const float* b1 = isU ? P.ub1 : P.ib1;
    const float* b2 = isU ? P.ub2 : P.ib2;
    const float* b3 = isU ? P.ub3 : P.ib3;
    short* Ybf = isU ? P.uY : P.iY;
    float* part = (isU ? P.uPart : P.iPart) + (size_t)bid * DK_;

    // ---- stage concat-x into LDS (swizzled 16B slots) ----
    const int CH_ROW = 1 << CHSH;
    for (int idx = t; idx < (16 << CHSH); idx += 256) {
        int row = idx >> CHSH;
        int slot = idx & (CH_ROW - 1);
        int a = slot >> 4, cs = slot & 15;
        const short* src = isU ? (a == 0 ? P.uA0 : a == 1 ? P.uA1 : a == 2 ? P.uA2 : P.uA3)
                               : (a == 0 ? P.iA0 : P.iA1);
        bh8 v = *(const bh8*)(src + (rb0 + row) * D_ + cs * 8);
        int sl2 = slot ^ (row & 7);
        *(bh8*)(xc + (row << (CHSH + 3)) + sl2 * 8) = v;
    }
    __syncthreads();

    // ---- gemm: tmp = xcat @ Wg + bg -> x2 (bf16) ----
    {
        f32x4 accA0 = {0,0,0,0}, accB0 = accA0, accA1 = accA0, accB1 = accA0;
#pragma unroll 4
        for (int kk = 0; kk < KKG; ++kk) {
            int slot = kk * 4 + lg;
            bh8 af = *(const bh8*)(xc + (lr << (CHSH + 3)) + ((slot ^ (lr & 7)) * 8));
            bh8 b0 = *(const bh8*)(Wg + (((size_t)(2 * w) * KKG + kk) * 64 + l) * 8);
            bh8 b1v = *(const bh8*)(Wg + (((size_t)(2 * w + 1) * KKG + kk) * 64 + l) * 8);
            if (kk & 1) { accB0 = mfma16(af, b0, accB0); accB1 = mfma16(af, b1v, accB1); }
            else        { accA0 = mfma16(af, b0, accA0); accA1 = mfma16(af, b1v, accA1); }
        }
#pragma unroll
        for (int r = 0; r < 4; ++r) {
            int row = lg * 4 + r;
            int c0 = (2 * w) * 16 + lr;
            int c1 = c0 + 16;
            x2[row * 128 + (((c0 >> 3) ^ (row & 7)) * 8) + (l & 7)] = f2b(accA0[r] + accB0[r] + bg[c0]);
            x2[row * 128 + (((c1 >> 3) ^ (row & 7)) * 8) + (l & 7)] = f2b(accA1[r] + accB1[r] + bg[c1]);
        }
    }
    __syncthreads();

    // ---- phase 1: h1 = tanh(x2 @ W1 + b1) ----
    {
        bh8 a1f[4];
#pragma unroll
        for (int kk = 0; kk < 4; ++kk) {
            int slot = kk * 4 + lg;
            a1f[kk] = *(const bh8*)(x2 + lr * 128 + (slot ^ (lr & 7)) * 8);
        }
#pragma unroll 2
        for (int tile = w * 20; tile < w * 20 + 20; ++tile) {
            float bv = b1[tile * 16 + lr];
            f32x4 acc = {bv, bv, bv, bv};
#pragma unroll
            for (int kk = 0; kk < 4; ++kk) {
                bh8 bf_ = *(const bh8*)(W1 + (((size_t)tile * 4 + kk) * 64 + l) * 8);
                acc = mfma16(a1f[kk], bf_, acc);
            }
#pragma unroll
            for (int r = 0; r < 4; ++r) {
                int row = lg * 4 + r;
                int col = tile * 16 + lr;
                h1[row * 1280 + (((col >> 3) ^ (row & 7)) * 8) + (l & 7)] = f2b(tanh_fast(acc[r]));
            }
        }
    }
    __syncthreads();

    // ---- phase 2: h2 = tanh(h1 @ W2 + b2) ----
    {
        float bv = b2[w * 16 + lr];
        f32x4 accA = {bv, bv, bv, bv}, accB = {0,0,0,0};
#pragma unroll 4
        for (int kk = 0; kk < 40; ++kk) {
            int slot = kk * 4 + lg;
            bh8 af = *(const bh8*)(h1 + lr * 1280 + (slot ^ (lr & 7)) * 8);
            bh8 bf_ = *(const bh8*)(W2 + (((size_t)w * 40 + kk) * 64 + l) * 8);
            if (kk & 1) accB = mfma16(af, bf_, accB);
            else        accA = mfma16(af, bf_, accA);
        }
#pragma unroll
        for (int r = 0; r < 4; ++r) {
            int row = lg * 4 + r;
            int col = w * 16 + lr;
            h2[row * 64 + (((col >> 3) ^ (row & 7)) * 8) + (l & 7)] = f2b(tanh_fast(accA[r] + accB[r]));
        }
    }
    __syncthreads();

    // ---- phase 3: y = h2 @ W3 + b3 -> ybuf(bf16), ssq ----
    {
        bh8 a3[2];
#pragma unroll
        for (int kk = 0; kk < 2; ++kk) {
            int slot = kk * 4 + lg;
            a3[kk] = *(const bh8*)(h2 + lr * 64 + (slot ^ (lr & 7)) * 8);
        }
        float ssq[4] = {0.f, 0.f, 0.f, 0.f};
#pragma unroll 2
        for (int tile = w * 20; tile < w * 20 + 20; ++tile) {
            float bv = b3[tile * 16 + lr];
            f32x4 acc = {bv, bv, bv, bv};
            bh8 b0 = *(const bh8*)(W3 + (((size_t)tile * 2 + 0) * 64 + l) * 8);
            bh8 b1v = *(const bh8*)(W3 + (((size_t)tile * 2 + 1) * 64 + l) * 8);
            acc = mfma16(a3[0], b0, acc);
            acc = mfma16(a3[1], b1v, acc);
            bh4 pk;
#pragma unroll
            for (int r = 0; r < 4; ++r) {
                ssq[r] = fmaf(acc[r], acc[r], ssq[r]);
                pk[r] = f2b(acc[r]);
            }
            *(bh4*)(yb + tile * 260 + l * 4) = pk;
        }
#pragma unroll
        for (int off = 1; off < 16; off <<= 1) {
#pragma unroll
            for (int r = 0; r < 4; ++r) ssq[r] += __shfl_xor(ssq[r], off);
        }
        if (lr == 0) {
#pragma unroll
            for (int r = 0; r < 4; ++r) wred[w][lg * 4 + r] = ssq[r];
        }
    }
    __syncthreads();
    if (t < 16) {
        float s = wred[0][t] + wred[1][t] + wred[2][t] + wred[3][t];
        nrms[t] = 1.f / fmaxf(sqrtf(s), 1e-12f);
    }
    __syncthreads();

    // ---- writeout: normalized bf16; per-block colsum partial (non-atomic) ----
    {
        float csum[5] = {0.f, 0.f, 0.f, 0.f, 0.f};
        for (int row = 0; row < 16; ++row) {
            float nv = nrms[row];
            int lph = (row >> 2) << 4;
            int r = row & 3;
#pragma unroll
            for (int ch = 0; ch < 5; ++ch) {
                int c = ch * 256 + t;
                int tile = c >> 4;
                int lanep = lph | (c & 15);
                float v = b2f(yb[tile * 260 + lanep * 4 + r]) * nv;
                Ybf[(rb0 + row) * DK_ + c] = f2b(v);
                csum[ch] += v;
            }
        }
#pragma unroll
        for (int ch = 0; ch < 5; ++ch) part[ch * 256 + t] = csum[ch];
    }
}

// ---------------- reduce per-block colsum partials -> bsu/bsi ----------------
__global__ __launch_bounds__(256) void finalize_bias(
    const float* __restrict__ partU, const float* __restrict__ partI,
    float* __restrict__ bsu, float* __restrict__ bsi, int NU, int NI)
{
    int c = blockIdx.x * 256 + threadIdx.x;     // grid.x = 5 -> c < 1280
    int z = blockIdx.z;
    const float* part = z ? partI : partU;
    float* dst = z ? bsi : bsu;
    int M = z ? NI : NU;
    int chunk = (M + gridDim.y - 1) / gridDim.y;
    int r0 = blockIdx.y * chunk;
    int r1 = min(M, r0 + chunk);
    if (r0 >= r1) return;
    float s = 0.f;
    for (int r = r0; r < r1; ++r) s += part[(size_t)r * DK_ + c];
    atomicAdd(&dst[c], s);
}

// ---------------- softmax u (over D, stride K) + i (over K, stride D), one launch ----------------
__global__ __launch_bounds__(64) void softmax_all(
    const short* __restrict__ Yu, const short* __restrict__ Yi,
    const float* __restrict__ bsu, const float* __restrict__ bsi,
    float invU, float invI,
    float* __restrict__ outu, float* __restrict__ outi, int U, int I)
{
    __shared__ float rowb[DK_];
    int b = blockIdx.x;
    int t = threadIdx.x;
    if (b < U) {
        size_t base = (size_t)b * DK_;
        for (int i = t; i < DK_ / 4; i += 64) {
            uint2 a = ((const uint2*)(Yu + base))[i];
            float4 bv = ((const float4*)bsu)[i];
            rowb[4 * i + 0] = b2f((short)(a.x & 0xffff)) + bv.x * invU;
            rowb[4 * i + 1] = b2f((short)(a.x >> 16))    + bv.y * invU;
            rowb[4 * i + 2] = b2f((short)(a.y & 0xffff)) + bv.z * invU;
            rowb[4 * i + 3] = b2f((short)(a.y >> 16))    + bv.w * invU;
        }
        __syncthreads();
#pragma unroll 1
        for (int k = 0; k < K_; ++k) {
            float v0 = rowb[t * K_ + k];
            float v1 = rowb[(t + 64) * K_ + k];
            float m = fmaxf(v0, v1);
            for (int off = 32; off; off >>= 1) m = fmaxf(m, __shfl_xor(m, off));
            float e0 = expf(v0 - m), e1 = expf(v1 - m);
            float s = e0 + e1;
            for (int off = 32; off; off >>= 1) s += __shfl_xor(s, off);
            float rs = 1.f / s;
            rowb[t * K_ + k] = e0 * rs;
            rowb[(t + 64) * K_ + k] = e1 * rs;
        }
        __syncthreads();
        for (int i = t; i < DK_ / 4; i += 64)
            ((float4*)(outu + base))[i] = ((const float4*)rowb)[i];
    } else {
        int it = b - U;
        if (it >= I) return;
        size_t base = (size_t)it * DK_;
        float v0[K_], v1[K_];
        float m0 = -1e30f, m1 = -1e30f;
#pragma unroll
        for (int k = 0; k < K_; ++k) {
            unsigned a = *(const unsigned*)(Yi + base + k * D_ + 2 * t);
            float2 bv = ((const float2*)(bsi + k * D_))[t];
            v0[k] = b2f((short)(a & 0xffff)) + bv.x * invI;
            v1[k] = b2f((short)(a >> 16))    + bv.y * invI;
            m0 = fmaxf(m0, v0[k]); m1 = fmaxf(m1, v1[k]);
        }
        float s0 = 0.f, s1 = 0.f;
#pragma unroll
        for (int k = 0; k < K_; ++k) {
            v0[k] = expf(v0[k] - m0); s0 += v0[k];
            v1[k] = expf(v1[k] - m1); s1 += v1[k];
        }
        float r0 = 1.f / s0, r1 = 1.f / s1;
#pragma unroll
        for (int k = 0; k < K_; ++k) {
            float2 o; o.x = v0[k] * r0; o.y = v1[k] * r1;
            ((float2*)(outi + base + k * D_))[t] = o;
        }
    }
}

extern "C" void kernel_launch(void* const* d_in, const int* in_sizes, int n_in,
                              void* d_out, int out_size, void* d_ws, size_t ws_size,
                              hipStream_t stream)
{
    const float* uemb_s   = (const float*)d_in[0];
    const float* iemb_s   = (const float*)d_in[1];
    const float* uemb_t   = (const float*)d_in[2];
    const float* u_emb_sp = (const float*)d_in[3];
    const int*   eu       = (const int*)d_in[4];
    const int*   ei       = (const int*)d_in[5];
    const float* Wu  = (const float*)d_in[6];
    const float* bu  = (const float*)d_in[7];
    const float* Wi  = (const float*)d_in[8];
    const float* bi  = (const float*)d_in[9];
    const float* m1w1 = (const float*)d_in[10];
    const float* m1b1 = (const float*)d_in[11];
    const float* m1w2 = (const float*)d_in[12];
    const float* m1b2 = (const float*)d_in[13];
    const float* m1w3 = (const float*)d_in[14];
    const float* m1b3 = (const float*)d_in[15];
    const float* m2w1 = (const float*)d_in[16];
    const float* m2b1 = (const float*)d_in[17];
    const float* m2w2 = (const float*)d_in[18];
    const float* m2b2 = (const float*)d_in[19];
    const float* m2w3 = (const float*)d_in[20];
    const float* m2b3 = (const float*)d_in[21];

    const int U = in_sizes[0] / D_;
    const int I = in_sizes[1] / D_;
    const int E = in_sizes[4];

    const int SHU = 9, SHI = 8;
    const int NBU = (U + 511) >> 9;
    const int NBI = (I + 255) >> 8;
    const int UB = U / 16, IB = I / 16;

    char* p = (char*)d_ws;
    auto alloc = [&](size_t bytes) { char* r = p; p += (bytes + 255) & ~(size_t)255; return r; };

    short* usb  = (short*)alloc((size_t)U * D_ * 2);
    short* utb  = (short*)alloc((size_t)U * D_ * 2);
    short* uspb = (short*)alloc((size_t)U * D_ * 2);
    short* uavg = (short*)alloc((size_t)U * D_ * 2);
    short* isb  = (short*)alloc((size_t)I * D_ * 2);
    short* nub  = (short*)alloc((size_t)U * D_ * 2);
    short* nib  = (short*)alloc((size_t)I * D_ * 2);
    short* ybu  = (short*)alloc((size_t)U * DK_ * 2);
    short* ybi  = (short*)alloc((size_t)I * DK_ * 2);
    float* partU = (float*)alloc((size_t)UB * DK_ * 4);
    float* partI = (float*)alloc((size_t)IB * DK_ * 4);
    short* WgU  = (short*)alloc(512 * 128 * 2);
    short* WgI  = (short*)alloc(256 * 128 * 2);
    short* W1U  = (short*)alloc(128 * 1280 * 2);
    short* W2U  = (short*)alloc(1280 * 64 * 2);
    short* W3U  = (short*)alloc(64 * 1280 * 2);
    short* W1I  = (short*)alloc(128 * 1280 * 2);
    short* W2I  = (short*)alloc(1280 * 64 * 2);
    short* W3I  = (short*)alloc(64 * 1280 * 2);
    int*   zbuf = (int*)alloc((320 + 2 * DK_) * 4);    // bcnt | bsu | bsi, one memset
    int* bcnt_u = zbuf;
    int* bcnt_i = zbuf + 160;
    float* bsu  = (float*)(zbuf + 320);
    float* bsi  = bsu + DK_;
    int* gcur_u = (int*)alloc(160 * 4);
    int* gcur_i = (int*)alloc(160 * 4);
    int* bbase_u = (int*)alloc(161 * 4);
    int* bbase_i = (int*)alloc(161 * 4);
    int* off_u  = (int*)alloc((size_t)U * 4);
    int* end_u  = (int*)alloc((size_t)U * 4);
    int* off_i  = (int*)alloc((size_t)I * 4);
    int* end_i  = (int*)alloc((size_t)I * 4);
    unsigned* ebu = (unsigned*)alloc((size_t)E * 4);
    unsigned* ebi = (unsigned*)alloc((size_t)E * 4);
    int* adj_u  = (int*)alloc((size_t)E * 4);
    int* adj_i  = (int*)alloc((size_t)E * 4);

    float* outu = (float*)d_out;
    float* outi = outu + (size_t)U * DK_;

    hipMemsetAsync(zbuf, 0, (320 + 2 * DK_) * 4, stream);

    int n4u = U * D_ / 4, n4i = I * D_ / 4;
    cvt_all<<<(n4u + n4i + 255) / 256, 256, 0, stream>>>(
        uemb_s, uemb_t, u_emb_sp, iemb_s, usb, utb, uspb, uavg, isb, n4u, n4i);

    PackArgs pa;
    pa.W[0] = Wu;   pa.o[0] = WgU; pa.K[0] = 512;  pa.N[0] = 128;
    pa.W[1] = Wi;   pa.o[1] = WgI; pa.K[1] = 256;  pa.N[1] = 128;
    pa.W[2] = m1w1; pa.o[2] = W1U; pa.K[2] = 128;  pa.N[2] = 1280;
    pa.W[3] = m1w2; pa.o[3] = W2U; pa.K[3] = 1280; pa.N[3] = 64;
    pa.W[4] = m1w3; pa.o[4] = W3U; pa.K[4] = 64;   pa.N[4] = 1280;
    pa.W[5] = m2w1; pa.o[5] = W1I; pa.K[5] = 128;  pa.N[5] = 1280;
    pa.W[6] = m2w2; pa.o[6] = W2I; pa.K[6] = 1280; pa.N[6] = 64;
    pa.W[7] = m2w3; pa.o[7] = W3I; pa.K[7] = 64;   pa.N[7] = 1280;
    pack_all<<<dim3(640, 8), 256, 0, stream>>>(pa);

    int pb = (E + 4095) / 4096;
    bhist_kernel<<<pb, 256, 0, stream>>>(eu, ei, bcnt_u, bcnt_i, E, SHU, SHI, NBU, NBI);
    binit_kernel<<<1, 256, 0, stream>>>(bcnt_u, gcur_u, bbase_u, NBU,
                                        bcnt_i, gcur_i, bbase_i, NBI, E);
    partition_kernel<<<pb, 256, 0, stream>>>(eu, ei, gcur_u, gcur_i, ebu, ebi,
                                             E, SHU, SHI, NBU, NBI);
    fill2_all<<<NBU + NBI, 256, 0, stream>>>(ebu, bbase_u, off_u, end_u, adj_u, NBU, U,
                                             ebi, bbase_i, off_i, end_i, adj_i, I);

    gather_all<<<(U + I + 3) / 4, 256, 0, stream>>>(
        isb, uavg, off_u, end_u, adj_u, off_i, end_i, adj_i, nub, nib, U, I);

    MlpArgs ma;
    ma.uA0 = usb; ma.uA1 = utb; ma.uA2 = uspb; ma.uA3 = nub;
    ma.iA0 = isb; ma.iA1 = nib;
    ma.uWg = WgU; ma.uW1 = W1U; ma.uW2 = W2U; ma.uW3 = W3U;
    ma.iWg = WgI; ma.iW1 = W1I; ma.iW2 = W2I; ma.iW3 = W3I;
    ma.ubg = bu; ma.ub1 = m1b1; ma.ub2 = m1b2; ma.ub3 = m1b3;
    ma.ibg = bi; ma.ib1 = m2b1; ma.ib2 = m2b2; ma.ib3 = m2b3;
    ma.uY = ybu; ma.iY = ybi;
    ma.uPart = partU; ma.iPart = partI;
    ma.UB = UB;
    fused_mlp_all<<<UB + IB, 256, 0, stream>>>(ma);

    finalize_bias<<<dim3(5, 40, 2), 256, 0, stream>>>(partU, partI, bsu, bsi, UB, IB);

    softmax_all<<<U + I, 64, 0, stream>>>(ybu, ybi, bsu, bsi,
                                          1.0f / (float)U, 1.0f / (float)I, outu, outi, U, I);
}